// Round 6
// baseline (532.228 us; speedup 1.0000x reference)
//
#include <hip/hip_runtime.h>

typedef __attribute__((ext_vector_type(8))) short short8;
typedef __attribute__((ext_vector_type(4))) float f32x4;
typedef __attribute__((ext_vector_type(4))) unsigned uint4v;

#define NWAVES 2
#define BLOCK (64 * NWAVES)
#define TB 8192                       // T buffer: 64 rows x 128 B bf16
#define WBYTES (TB + 6 * 64 * 4)      // + mask area mkT[6][64] u32 = 9728 B/wave

__device__ __forceinline__ unsigned short f2bf(float f) {
    unsigned u = __builtin_bit_cast(unsigned, f);
    u += 0x7FFFu + ((u >> 16) & 1u);          // round-to-nearest-even
    return (unsigned short)(u >> 16);
}

// swizzled T-buffer byte address: row in [0,64), slot = 16B unit of 8 bf16
__device__ __forceinline__ int taddr(int row, int slot) {
    return row * 128 + (((slot ^ (row & 7)) << 4));
}

// bf16 B-fragment for mfma_f32_16x16x32_bf16: B[k][n], lane gives (col, kbase).
__device__ __forceinline__ short8 loadB(const float* __restrict__ W, int Nout, int Kin,
                                        int kbase, int col) {
    short8 r;
#pragma unroll
    for (int i = 0; i < 8; ++i) {
        int k = kbase + i;
        float v = (k < Kin && col < Nout) ? W[k * Nout + col] : 0.0f;
        r[i] = (short)f2bf(v);
    }
    return r;
}

// ---------- forward layer in registers (exact fp32, blocked 16-wide) --------
// FULL unroll everywhere (rule #20). VGPR cap must be >=256 band: at cap 128
// (launch_bounds min-waves 3) the allocator spills the whole activation set
// to scratch -> 600 MB HBM traffic (rounds 4/5).
template<int K, int N>
__device__ __forceinline__ void fwd_layer_reg(const float* __restrict__ W,
                                              const float* __restrict__ b,
                                              const float (&in)[K], float (&out)[N],
                                              unsigned long long& mask)
{
    mask = 0ULL;
#pragma unroll
    for (int jb = 0; jb < N; jb += 16) {
        float acc[16];
#pragma unroll
        for (int j = 0; j < 16; ++j) acc[j] = b[jb + j];
#pragma unroll
        for (int k = 0; k < K; ++k) {
            const float cv = in[k];
#pragma unroll
            for (int j = 0; j < 16; ++j) acc[j] = fmaf(cv, W[k * N + jb + j], acc[j]);
        }
#pragma unroll
        for (int j = 0; j < 16; ++j) {
            const bool p = acc[j] > 0.0f;
            mask |= ((unsigned long long)(p ? 1 : 0)) << (jb + j);
            out[jb + j] = p ? acc[j] : 0.0f;
        }
    }
}

// ---------- tangent epilogue: mask (one b128 read), cvt bf16, swizzled write -
// C/D layout (verified): col = lane&15, row = (lane>>4)*4 + reg.  Rows = samples.
template<int WORD0, int WSHIFT>
__device__ __forceinline__ void epi_store(unsigned char* wb, const unsigned* mkT,
                                          f32x4 c, int mt, int nt, int lane)
{
    const int col = lane & 15, G = lane >> 4;
    const int unit = nt * 16 + col;
    const int word = WORD0 + (WSHIFT ? (unit >> 5) : 0);
    const int bit  = unit & 31;
    const int R0 = mt * 16 + G * 4;
    const uint4v mw = *(const uint4v*)(mkT + word * 64 + R0);
    const int slot = unit >> 3;
    const int off = (unit & 7) * 2;
#pragma unroll
    for (int i = 0; i < 4; ++i) {
        const int R = R0 + i;
        const float v = ((mw[i] >> bit) & 1u) ? c[i] : 0.0f;
        *(unsigned short*)(wb + R * 128 + (((slot ^ (R & 7)) << 4) | off)) = f2bf(v);
    }
}

// ---------- one tangent GEMM layer, in-place in the 64-row T buffer ---------
template<int KT, int NT, int WORD0, int WSHIFT>
__device__ __forceinline__ void tan_layer_mfma(unsigned char* wb, const unsigned* mkT,
                                               const short8* Bf, int lane)
{
    const int G = lane >> 4;
    const int r15 = lane & 15;
#pragma unroll
    for (int mt = 0; mt < 4; ++mt) {
        const int R = mt * 16 + r15;
        short8 a[KT];
#pragma unroll
        for (int kt = 0; kt < KT; ++kt)
            a[kt] = *(const short8*)(wb + taddr(R, 4 * kt + G));
#pragma unroll
        for (int nt = 0; nt < NT; ++nt) {
            f32x4 c = {0.f, 0.f, 0.f, 0.f};
#pragma unroll
            for (int kt = 0; kt < KT; ++kt)
                c = __builtin_amdgcn_mfma_f32_16x16x32_bf16(a[kt], Bf[kt * NT + nt], c, 0, 0, 0);
            epi_store<WORD0, WSHIFT>(wb, mkT, c, mt, nt, lane);
        }
    }
}

// ---------- final layer: T4 @ W5 -> F column r (adds identity) --------------
__device__ __forceinline__ void tan_final(unsigned char* wb, const short8* B5,
                                          int lane, int r,
                                          float* __restrict__ out_F, int sbase)
{
    const int G = lane >> 4, col = lane & 15;
    const int r15 = lane & 15;
#pragma unroll
    for (int mt = 0; mt < 4; ++mt) {
        const int R = mt * 16 + r15;
        short8 a0 = *(const short8*)(wb + taddr(R, G));
        short8 a1 = *(const short8*)(wb + taddr(R, 4 + G));
        f32x4 c = {0.f, 0.f, 0.f, 0.f};
        c = __builtin_amdgcn_mfma_f32_16x16x32_bf16(a0, B5[0], c, 0, 0, 0);
        c = __builtin_amdgcn_mfma_f32_16x16x32_bf16(a1, B5[1], c, 0, 0, 0);
        if (col < 4) {
            const int R0 = mt * 16 + G * 4;
#pragma unroll
            for (int i = 0; i < 4; ++i) {
                const float v = c[i] + ((col == r) ? 1.0f : 0.0f);
                out_F[(size_t)(sbase + R0 + i) * 16 + col * 4 + r] = v;
            }
        }
    }
}

__global__ __launch_bounds__(BLOCK, 2)   // VGPR cap 256: forward set fits in regs
void mlp_jac_kernel(
    const float* __restrict__ W1, const float* __restrict__ b1,
    const float* __restrict__ W2, const float* __restrict__ b2,
    const float* __restrict__ W3, const float* __restrict__ b3,
    const float* __restrict__ W4, const float* __restrict__ b4,
    const float* __restrict__ W5, const float* __restrict__ b5,
    const float* __restrict__ xin,
    float* __restrict__ out_state, float* __restrict__ out_F, int Btot)
{
    __shared__ __align__(16) unsigned char smem[NWAVES][WBYTES];
    const int tid = threadIdx.x;
    const int wid = tid >> 6;
    const int lane = tid & 63;
    const int sbase = blockIdx.x * BLOCK + wid * 64;   // wave's first sample
    if (sbase >= Btot) return;

    unsigned char* wb = smem[wid];
    unsigned* mkT = (unsigned*)(wb + TB);              // mkT[word][sample]

    const int s_my = sbase + lane;
    const float4 xv = *reinterpret_cast<const float4*>(xin + 4 * s_my);
    float xa[4] = {xv.x, xv.y, xv.z, xv.w};

    // ============ phase 1: fp32 forward entirely in registers ==============
    unsigned long long m1w, m2w, m3, m4;
    float h1[32], h2[32], h3[64];
    fwd_layer_reg<4, 32>(W1, b1, xa, h1, m1w);
    fwd_layer_reg<32, 32>(W2, b2, h1, h2, m2w);
    fwd_layer_reg<32, 64>(W3, b3, h2, h3, m3);
    const unsigned m1 = (unsigned)m1w, m2 = (unsigned)m2w;

    // layer4 + layer5 fused: h4 never materialized (full unroll, see above)
    m4 = 0ULL;
    float y[4] = {b5[0], b5[1], b5[2], b5[3]};
#pragma unroll
    for (int jb = 0; jb < 64; jb += 16) {
        float acc[16];
#pragma unroll
        for (int j = 0; j < 16; ++j) acc[j] = b4[jb + j];
#pragma unroll
        for (int k = 0; k < 64; ++k) {
            const float cv = h3[k];
#pragma unroll
            for (int j = 0; j < 16; ++j) acc[j] = fmaf(cv, W4[k * 64 + jb + j], acc[j]);
        }
#pragma unroll
        for (int j = 0; j < 16; ++j) {
            const bool p = acc[j] > 0.0f;
            m4 |= ((unsigned long long)(p ? 1 : 0)) << (jb + j);
            const float hv = p ? acc[j] : 0.0f;
#pragma unroll
            for (int i = 0; i < 4; ++i) y[i] = fmaf(hv, W5[(jb + j) * 4 + i], y[i]);
        }
    }
    {
        float4 o;
        o.x = xa[0] + y[0]; o.y = xa[1] + y[1];
        o.z = xa[2] + y[2]; o.w = xa[3] + y[3];
        *reinterpret_cast<float4*>(out_state + 4 * s_my) = o;
    }
    // masks word-major: one ds_read_b128 in the epilogue covers 4 samples
    mkT[0 * 64 + lane] = m1;
    mkT[1 * 64 + lane] = m2;
    mkT[2 * 64 + lane] = (unsigned)(m3 & 0xffffffffULL);
    mkT[3 * 64 + lane] = (unsigned)(m3 >> 32);
    mkT[4 * 64 + lane] = (unsigned)(m4 & 0xffffffffULL);
    mkT[5 * 64 + lane] = (unsigned)(m4 >> 32);

    // Keep the tangent-phase B-fragment loads (64 VGPRs) out of the
    // forward's peak-pressure region.
    __builtin_amdgcn_sched_barrier(0);

    // ============ phase 2: bf16 weight B-fragments in registers ============
    const int col = lane & 15, G = lane >> 4;
    short8 B2f[2], B3f[4], B4f[8], B5f[2];
#pragma unroll
    for (int nt = 0; nt < 2; ++nt) B2f[nt] = loadB(W2, 32, 32, 8 * G, 16 * nt + col);
#pragma unroll
    for (int nt = 0; nt < 4; ++nt) B3f[nt] = loadB(W3, 64, 32, 8 * G, 16 * nt + col);
#pragma unroll
    for (int kt = 0; kt < 2; ++kt)
#pragma unroll
        for (int nt = 0; nt < 4; ++nt)
            B4f[kt * 4 + nt] = loadB(W4, 64, 64, 32 * kt + 8 * G, 16 * nt + col);
#pragma unroll
    for (int kt = 0; kt < 2; ++kt) B5f[kt] = loadB(W5, 4, 64, 32 * kt + 8 * G, col);

    // ============ phase 3: one Jacobian column per pass ====================
    for (int r = 0; r < 4; ++r) {
        // T1[s][u] = m1[s][u] ? bf16(W1[r][u]) : 0  — identical for all rows,
        // so seed by direct masked write (each lane writes its own row).
#pragma unroll
        for (int sl = 0; sl < 4; ++sl) {
            short8 v;
#pragma unroll
            for (int e = 0; e < 8; ++e) {
                const int u = sl * 8 + e;
                v[e] = ((m1 >> u) & 1u) ? (short)f2bf(W1[r * 32 + u]) : (short)0;
            }
            *(short8*)(wb + taddr(lane, sl)) = v;
        }
        // T2 = m2 .* (T1 @ W2); T3 = m3 .* (T2 @ W3); T4 = m4 .* (T3 @ W4)
        tan_layer_mfma<1, 2, 1, 0>(wb, mkT, B2f, lane);
        tan_layer_mfma<1, 4, 2, 1>(wb, mkT, B3f, lane);
        tan_layer_mfma<2, 4, 4, 1>(wb, mkT, B4f, lane);
        // F[:, :, r] = I[:, r] + T4 @ W5
        tan_final(wb, B5f, lane, r, out_F, sbase);
    }
}

extern "C" void kernel_launch(void* const* d_in, const int* in_sizes, int n_in,
                              void* d_out, int out_size, void* d_ws, size_t ws_size,
                              hipStream_t stream)
{
    const float* W1 = (const float*)d_in[0];
    const float* b1 = (const float*)d_in[1];
    const float* W2 = (const float*)d_in[2];
    const float* b2 = (const float*)d_in[3];
    const float* W3 = (const float*)d_in[4];
    const float* b3 = (const float*)d_in[5];
    const float* W4 = (const float*)d_in[6];
    const float* b4 = (const float*)d_in[7];
    const float* W5 = (const float*)d_in[8];
    const float* b5 = (const float*)d_in[9];
    const float* xin = (const float*)d_in[10];

    const int Btot = in_sizes[10] / 4;       // last_state is (B,1,4) fp32
    float* out_state = (float*)d_out;
    float* out_F = out_state + (size_t)Btot * 4;

    const int grid = (Btot + BLOCK - 1) / BLOCK;
    mlp_jac_kernel<<<grid, BLOCK, 0, stream>>>(
        W1, b1, W2, b2, W3, b3, W4, b4, W5, b5, xin, out_state, out_F, Btot);
}

// Round 7
// 117.150 us; speedup vs baseline: 4.5431x; 4.5431x over previous
//
#include <hip/hip_runtime.h>

typedef __attribute__((ext_vector_type(8))) short short8;
typedef __attribute__((ext_vector_type(4))) float f32x4;
typedef __attribute__((ext_vector_type(4))) unsigned uint4v;

#define NWAVES 2
#define BLOCK (64 * NWAVES)
#define TB 8192                     // tangent T buffer: 64 rows x 128 B bf16
#define FWDU 34                     // fp32 fwd units kept in LDS (rest in regs)
#define FWDB (FWDU * 64 * 4)        // 8704 B, overlaps T region (disjoint in time)
#define WBYTES (FWDB + 6 * 64 * 4)  // + masks mkT[6][64] -> 10240 B/wave
// block LDS = 20480 B -> 8 blocks/CU ceiling (163840/20480), vs round-2's 4.

__device__ __forceinline__ unsigned short f2bf(float f) {
    unsigned u = __builtin_bit_cast(unsigned, f);
    u += 0x7FFFu + ((u >> 16) & 1u);          // round-to-nearest-even
    return (unsigned short)(u >> 16);
}

// swizzled T-buffer byte address: row in [0,64), slot = 16B unit of 8 bf16
__device__ __forceinline__ int taddr(int row, int slot) {
    return row * 128 + (((slot ^ (row & 7)) << 4));
}

// bf16 B-fragment for mfma_f32_16x16x32_bf16: B[k][n], lane gives (col, kbase).
__device__ __forceinline__ short8 loadB(const float* __restrict__ W, int Nout, int Kin,
                                        int kbase, int col) {
    short8 r;
#pragma unroll
    for (int i = 0; i < 8; ++i) {
        int k = kbase + i;
        float v = (k < Kin && col < Nout) ? W[k * Nout + col] : 0.0f;
        r[i] = (short)f2bf(v);
    }
    return r;
}

// ---------- tangent epilogue: mask (one b128 read), cvt bf16, swizzled write -
// C/D layout (verified): col = lane&15, row = (lane>>4)*4 + reg.  Rows = samples.
template<int WORD0, int WSHIFT>
__device__ __forceinline__ void epi_store(unsigned char* wb, const unsigned* mkT,
                                          f32x4 c, int mt, int nt, int lane)
{
    const int col = lane & 15, G = lane >> 4;
    const int unit = nt * 16 + col;
    const int word = WORD0 + (WSHIFT ? (unit >> 5) : 0);
    const int bit  = unit & 31;
    const int R0 = mt * 16 + G * 4;
    const uint4v mw = *(const uint4v*)(mkT + word * 64 + R0);
    const int slot = unit >> 3;
    const int off = (unit & 7) * 2;
#pragma unroll
    for (int i = 0; i < 4; ++i) {
        const int R = R0 + i;
        const float v = ((mw[i] >> bit) & 1u) ? c[i] : 0.0f;
        *(unsigned short*)(wb + R * 128 + (((slot ^ (R & 7)) << 4) | off)) = f2bf(v);
    }
}

// ---------- one tangent GEMM layer, in-place in the 64-row T buffer ---------
template<int KT, int NT, int WORD0, int WSHIFT>
__device__ __forceinline__ void tan_layer_mfma(unsigned char* wb, const unsigned* mkT,
                                               const short8* Bf, int lane)
{
    const int G = lane >> 4;
    const int r15 = lane & 15;
#pragma unroll
    for (int mt = 0; mt < 4; ++mt) {
        const int R = mt * 16 + r15;
        short8 a[KT];
#pragma unroll
        for (int kt = 0; kt < KT; ++kt)
            a[kt] = *(const short8*)(wb + taddr(R, 4 * kt + G));
#pragma unroll
        for (int nt = 0; nt < NT; ++nt) {
            f32x4 c = {0.f, 0.f, 0.f, 0.f};
#pragma unroll
            for (int kt = 0; kt < KT; ++kt)
                c = __builtin_amdgcn_mfma_f32_16x16x32_bf16(a[kt], Bf[kt * NT + nt], c, 0, 0, 0);
            epi_store<WORD0, WSHIFT>(wb, mkT, c, mt, nt, lane);
        }
    }
}

// ---------- final layer: T4 @ W5 -> F column r (adds identity) --------------
__device__ __forceinline__ void tan_final(unsigned char* wb, const short8* B5,
                                          int lane, int r,
                                          float* __restrict__ out_F, int sbase)
{
    const int G = lane >> 4, col = lane & 15;
    const int r15 = lane & 15;
#pragma unroll
    for (int mt = 0; mt < 4; ++mt) {
        const int R = mt * 16 + r15;
        short8 a0 = *(const short8*)(wb + taddr(R, G));
        short8 a1 = *(const short8*)(wb + taddr(R, 4 + G));
        f32x4 c = {0.f, 0.f, 0.f, 0.f};
        c = __builtin_amdgcn_mfma_f32_16x16x32_bf16(a0, B5[0], c, 0, 0, 0);
        c = __builtin_amdgcn_mfma_f32_16x16x32_bf16(a1, B5[1], c, 0, 0, 0);
        if (col < 4) {
            const int R0 = mt * 16 + G * 4;
#pragma unroll
            for (int i = 0; i < 4; ++i) {
                const float v = c[i] + ((col == r) ? 1.0f : 0.0f);
                out_F[(size_t)(sbase + R0 + i) * 16 + col * 4 + r] = v;
            }
        }
    }
}

__global__ __launch_bounds__(BLOCK)
void mlp_jac_kernel(
    const float* __restrict__ W1, const float* __restrict__ b1,
    const float* __restrict__ W2, const float* __restrict__ b2,
    const float* __restrict__ W3, const float* __restrict__ b3,
    const float* __restrict__ W4, const float* __restrict__ b4,
    const float* __restrict__ W5, const float* __restrict__ b5,
    const float* __restrict__ xin,
    float* __restrict__ out_state, float* __restrict__ out_F, int Btot)
{
    __shared__ __align__(16) unsigned char smem[NWAVES][WBYTES];
    const int tid = threadIdx.x;
    const int wid = tid >> 6;
    const int lane = tid & 63;
    const int sbase = blockIdx.x * BLOCK + wid * 64;   // wave's first sample
    if (sbase >= Btot) return;

    unsigned char* wb = smem[wid];
    float* fbuf = (float*)wb;                          // fwd acts [unit][lane] fp32
    unsigned* mkT = (unsigned*)(wb + FWDB);            // masks, word-major [word][sample]

    const int s_my = sbase + lane;
    const float4 xv = *reinterpret_cast<const float4*>(xin + 4 * s_my);
    const float xa[4] = {xv.x, xv.y, xv.z, xv.w};

    // ============ phase 1: fp32 forward (LDS activations, rolled k-loops) ===
    // Proven round-2 structure: unit-major buf (conflict-free b32), weights
    // via wave-uniform s_load. Register-array forwards (r4-r6) all regressed.
    unsigned m1, m2;
    unsigned long long m3, m4;
    // ---- L1: 4 -> 32 (tiny, fully unrolled) ----
    {
        float acc[32];
#pragma unroll
        for (int j = 0; j < 32; ++j) {
            float a = b1[j];
#pragma unroll
            for (int k = 0; k < 4; ++k) a = fmaf(xa[k], W1[k * 32 + j], a);
            acc[j] = a;
        }
        unsigned m = 0;
#pragma unroll
        for (int j = 0; j < 32; ++j) {
            const bool p = acc[j] > 0.0f;
            m |= ((unsigned)(p ? 1 : 0)) << j;
            fbuf[j * 64 + lane] = p ? acc[j] : 0.0f;
        }
        m1 = m;
    }
    // ---- L2: 32 -> 32, in-place ----
    {
        float acc[32];
#pragma unroll
        for (int j = 0; j < 32; ++j) acc[j] = b2[j];
#pragma unroll 2
        for (int k = 0; k < 32; ++k) {
            const float cv = fbuf[k * 64 + lane];
#pragma unroll
            for (int j = 0; j < 32; ++j) acc[j] = fmaf(cv, W2[k * 32 + j], acc[j]);
        }
        unsigned m = 0;
#pragma unroll
        for (int j = 0; j < 32; ++j) {
            const bool p = acc[j] > 0.0f;
            m |= ((unsigned)(p ? 1 : 0)) << j;
            fbuf[j * 64 + lane] = p ? acc[j] : 0.0f;
        }
        m2 = m;
    }
    // ---- L3: 32 -> 64; units 0..33 to LDS, 34..63 stay in registers ----
    float h3r[64 - FWDU];
    {
        float acc[64];
#pragma unroll
        for (int j = 0; j < 64; ++j) acc[j] = b3[j];
#pragma unroll 2
        for (int k = 0; k < 32; ++k) {
            const float cv = fbuf[k * 64 + lane];
#pragma unroll
            for (int j = 0; j < 64; ++j) acc[j] = fmaf(cv, W3[k * 64 + j], acc[j]);
        }
        unsigned long long m = 0ULL;
#pragma unroll
        for (int j = 0; j < 64; ++j) {
            const bool p = acc[j] > 0.0f;
            m |= ((unsigned long long)(p ? 1 : 0)) << j;
            const float hv = p ? acc[j] : 0.0f;
            if (j < FWDU) fbuf[j * 64 + lane] = hv;
            else          h3r[j - FWDU] = hv;
        }
        m3 = m;
    }
    // ---- L4 + L5 fused: h4 never materialized ----
    {
        float acc[64];
#pragma unroll
        for (int j = 0; j < 64; ++j) acc[j] = b4[j];
#pragma unroll 2
        for (int k = 0; k < FWDU; ++k) {
            const float cv = fbuf[k * 64 + lane];
#pragma unroll
            for (int j = 0; j < 64; ++j) acc[j] = fmaf(cv, W4[k * 64 + j], acc[j]);
        }
#pragma unroll
        for (int t = 0; t < 64 - FWDU; ++t) {       // k = FWDU+t, compile-time
            const float cv = h3r[t];
#pragma unroll
            for (int j = 0; j < 64; ++j) acc[j] = fmaf(cv, W4[(FWDU + t) * 64 + j], acc[j]);
        }
        unsigned long long m = 0ULL;
        float y[4] = {b5[0], b5[1], b5[2], b5[3]};
#pragma unroll
        for (int j = 0; j < 64; ++j) {
            const bool p = acc[j] > 0.0f;
            m |= ((unsigned long long)(p ? 1 : 0)) << j;
            const float hv = p ? acc[j] : 0.0f;
#pragma unroll
            for (int i = 0; i < 4; ++i) y[i] = fmaf(hv, W5[j * 4 + i], y[i]);
        }
        m4 = m;
        float4 o;
        o.x = xa[0] + y[0]; o.y = xa[1] + y[1];
        o.z = xa[2] + y[2]; o.w = xa[3] + y[3];
        *reinterpret_cast<float4*>(out_state + 4 * s_my) = o;
    }
    // masks word-major: one ds_read_b128 in the epilogue covers 4 samples
    mkT[0 * 64 + lane] = m1;
    mkT[1 * 64 + lane] = m2;
    mkT[2 * 64 + lane] = (unsigned)(m3 & 0xffffffffULL);
    mkT[3 * 64 + lane] = (unsigned)(m3 >> 32);
    mkT[4 * 64 + lane] = (unsigned)(m4 & 0xffffffffULL);
    mkT[5 * 64 + lane] = (unsigned)(m4 >> 32);

    // Keep tangent-phase B-fragment loads (64 VGPRs) out of the forward.
    __builtin_amdgcn_sched_barrier(0);

    // ============ phase 2: bf16 weight B-fragments in registers ============
    const int col = lane & 15, G = lane >> 4;
    short8 B2f[2], B3f[4], B4f[8], B5f[2];
#pragma unroll
    for (int nt = 0; nt < 2; ++nt) B2f[nt] = loadB(W2, 32, 32, 8 * G, 16 * nt + col);
#pragma unroll
    for (int nt = 0; nt < 4; ++nt) B3f[nt] = loadB(W3, 64, 32, 8 * G, 16 * nt + col);
#pragma unroll
    for (int kt = 0; kt < 2; ++kt)
#pragma unroll
        for (int nt = 0; nt < 4; ++nt)
            B4f[kt * 4 + nt] = loadB(W4, 64, 64, 32 * kt + 8 * G, 16 * nt + col);
#pragma unroll
    for (int kt = 0; kt < 2; ++kt) B5f[kt] = loadB(W5, 4, 64, 32 * kt + 8 * G, col);

    // ============ phase 3: one Jacobian column per pass ====================
    // T region = wb[0..8192) — overlaps the (now dead) fwd buffer.
    for (int r = 0; r < 4; ++r) {
        // T1[s][u] = m1[s][u] ? bf16(W1[r][u]) : 0 — direct masked seed write.
#pragma unroll
        for (int sl = 0; sl < 4; ++sl) {
            short8 v;
#pragma unroll
            for (int e = 0; e < 8; ++e) {
                const int u = sl * 8 + e;
                v[e] = ((m1 >> u) & 1u) ? (short)f2bf(W1[r * 32 + u]) : (short)0;
            }
            *(short8*)(wb + taddr(lane, sl)) = v;
        }
        // T2 = m2 .* (T1 @ W2); T3 = m3 .* (T2 @ W3); T4 = m4 .* (T3 @ W4)
        tan_layer_mfma<1, 2, 1, 0>(wb, mkT, B2f, lane);
        tan_layer_mfma<1, 4, 2, 1>(wb, mkT, B3f, lane);
        tan_layer_mfma<2, 4, 4, 1>(wb, mkT, B4f, lane);
        // F[:, :, r] = I[:, r] + T4 @ W5
        tan_final(wb, B5f, lane, r, out_F, sbase);
    }
}

extern "C" void kernel_launch(void* const* d_in, const int* in_sizes, int n_in,
                              void* d_out, int out_size, void* d_ws, size_t ws_size,
                              hipStream_t stream)
{
    const float* W1 = (const float*)d_in[0];
    const float* b1 = (const float*)d_in[1];
    const float* W2 = (const float*)d_in[2];
    const float* b2 = (const float*)d_in[3];
    const float* W3 = (const float*)d_in[4];
    const float* b3 = (const float*)d_in[5];
    const float* W4 = (const float*)d_in[6];
    const float* b4 = (const float*)d_in[7];
    const float* W5 = (const float*)d_in[8];
    const float* b5 = (const float*)d_in[9];
    const float* xin = (const float*)d_in[10];

    const int Btot = in_sizes[10] / 4;       // last_state is (B,1,4) fp32
    float* out_state = (float*)d_out;
    float* out_F = out_state + (size_t)Btot * 4;

    const int grid = (Btot + BLOCK - 1) / BLOCK;
    mlp_jac_kernel<<<grid, BLOCK, 0, stream>>>(
        W1, b1, W2, b2, W3, b3, W4, b4, W5, b5, xin, out_state, out_F, Btot);
}

// Round 8
// 108.369 us; speedup vs baseline: 4.9113x; 1.0810x over previous
//
#include <hip/hip_runtime.h>

typedef __attribute__((ext_vector_type(8))) short short8;
typedef __attribute__((ext_vector_type(4))) float f32x4;
typedef __attribute__((ext_vector_type(2))) unsigned uint2v;

#define NWAVES 2
#define BLOCK (64 * NWAVES)
#define TB 8192                     // tangent T buffer: 64 rows x 128 B bf16
#define FWDU 34                     // fp32 fwd units kept in LDS (rest in regs)
#define FWDB (FWDU * 64 * 4)        // 8704 B, overlaps T region (disjoint in time)
#define WBYTES (FWDB + 6 * 64 * 4)  // + masks mkS[64][6] -> 10240 B/wave

__device__ __forceinline__ unsigned short f2bf(float f) {
    unsigned u = __builtin_bit_cast(unsigned, f);
    u += 0x7FFFu + ((u >> 16) & 1u);          // round-to-nearest-even
    return (unsigned short)(u >> 16);
}

// swizzled T-buffer byte address: row in [0,64), slot = 16B unit of 8 bf16
__device__ __forceinline__ int taddr(int row, int slot) {
    return row * 128 + (((slot ^ (row & 7)) << 4));
}

// bf16 weight fragment: element [k][col] of W (row-major KxN), zero-padded.
// Per-lane pattern (16-dim = lane&15, k = kbase+0..7) serves either MFMA operand.
__device__ __forceinline__ short8 loadB(const float* __restrict__ W, int Nout, int Kin,
                                        int kbase, int col) {
    short8 r;
#pragma unroll
    for (int i = 0; i < 8; ++i) {
        int k = kbase + i;
        float v = (k < Kin && col < Nout) ? W[k * Nout + col] : 0.0f;
        r[i] = (short)f2bf(v);
    }
    return r;
}

// ---------- transposed tangent layer: T_next^T = mask .* (W^T @ T^T) --------
// A = weight fragments (regs, rows = next units), B = T rows from LDS
// (row = sample, contiguous b128). C/D: col = sample, rows = 4 consecutive
// next-units -> epilogue is one ds_write_b64 + 2 cvt_pk per fragment.
// In-place safe: each nt reads rows 16nt..16nt+15 (program order) before
// writing the same rows.
template<int MT, int KT, int W0, int NW>
__device__ __forceinline__ void tan_layer_T(unsigned char* wb, const unsigned* mkS,
                                            const short8* Wf, int lane)
{
    const int G = lane >> 4, sl = lane & 15;
#pragma unroll
    for (int nt = 0; nt < 4; ++nt) {
        const int s = nt * 16 + sl;                    // sample row
        short8 bt[KT];
#pragma unroll
        for (int kt = 0; kt < KT; ++kt)
            bt[kt] = *(const short8*)(wb + taddr(s, 4 * kt + G));
        unsigned mwords[NW];
#pragma unroll
        for (int w = 0; w < NW; ++w) mwords[w] = mkS[s * 6 + W0 + w];
#pragma unroll
        for (int mt = 0; mt < MT; ++mt) {
            f32x4 c = {0.f, 0.f, 0.f, 0.f};
#pragma unroll
            for (int kt = 0; kt < KT; ++kt)
                c = __builtin_amdgcn_mfma_f32_16x16x32_bf16(Wf[kt * MT + mt], bt[kt], c, 0, 0, 0);
            // mask + pack + single b64 write of units u0..u0+3 of sample s
            const unsigned mw = mwords[(mt * 16) >> 5] >> ((mt & 1) * 16 + G * 4);
            const float v0 = (mw & 1u) ? c[0] : 0.0f;
            const float v1 = (mw & 2u) ? c[1] : 0.0f;
            const float v2 = (mw & 4u) ? c[2] : 0.0f;
            const float v3 = (mw & 8u) ? c[3] : 0.0f;
            unsigned lo, hi;
            asm("v_cvt_pk_bf16_f32 %0, %1, %2" : "=v"(lo) : "v"(v0), "v"(v1));
            asm("v_cvt_pk_bf16_f32 %0, %1, %2" : "=v"(hi) : "v"(v2), "v"(v3));
            const int slot = 2 * mt + (G >> 1);
            uint2v pk; pk[0] = lo; pk[1] = hi;
            *(uint2v*)(wb + s * 128 + ((slot ^ (s & 7)) << 4) + 8 * (G & 1)) = pk;
        }
    }
}

// ---------- final layer (transposed): F col r = I[:,r] + (W5^T @ T4^T)^T ----
__device__ __forceinline__ void tan_final_T(unsigned char* wb, const short8* B5,
                                            int lane, int r,
                                            float* __restrict__ out_F, int sbase)
{
    const int G = lane >> 4, sl = lane & 15;
#pragma unroll
    for (int nt = 0; nt < 4; ++nt) {
        const int s = nt * 16 + sl;
        short8 b0 = *(const short8*)(wb + taddr(s, G));
        short8 b1 = *(const short8*)(wb + taddr(s, 4 + G));
        f32x4 c = {0.f, 0.f, 0.f, 0.f};
        c = __builtin_amdgcn_mfma_f32_16x16x32_bf16(B5[0], b0, c, 0, 0, 0);
        c = __builtin_amdgcn_mfma_f32_16x16x32_bf16(B5[1], b1, c, 0, 0, 0);
        if (G == 0) {                                  // rows 0-3 = out dims
#pragma unroll
            for (int i = 0; i < 4; ++i)
                out_F[(size_t)(sbase + s) * 16 + i * 4 + r] = c[i] + ((i == r) ? 1.0f : 0.0f);
        }
    }
}

__global__ __launch_bounds__(BLOCK)
void mlp_jac_kernel(
    const float* __restrict__ W1, const float* __restrict__ b1,
    const float* __restrict__ W2, const float* __restrict__ b2,
    const float* __restrict__ W3, const float* __restrict__ b3,
    const float* __restrict__ W4, const float* __restrict__ b4,
    const float* __restrict__ W5, const float* __restrict__ b5,
    const float* __restrict__ xin,
    float* __restrict__ out_state, float* __restrict__ out_F, int Btot)
{
    __shared__ __align__(16) unsigned char smem[NWAVES][WBYTES];
    const int tid = threadIdx.x;
    const int wid = tid >> 6;
    const int lane = tid & 63;
    const int sbase = blockIdx.x * BLOCK + wid * 64;   // wave's first sample
    if (sbase >= Btot) return;

    unsigned char* wb = smem[wid];
    float* fbuf = (float*)wb;                          // fwd acts [unit][lane] fp32
    unsigned* mkS = (unsigned*)(wb + FWDB);            // masks, sample-major [s][6]

    const int s_my = sbase + lane;
    const float4 xv = *reinterpret_cast<const float4*>(xin + 4 * s_my);
    const float xa[4] = {xv.x, xv.y, xv.z, xv.w};

    // ============ phase 1: fp32 forward (round-7 proven structure) =========
    unsigned m1, m2;
    unsigned long long m3, m4;
    // ---- L1: 4 -> 32 ----
    {
        float acc[32];
#pragma unroll
        for (int j = 0; j < 32; ++j) {
            float a = b1[j];
#pragma unroll
            for (int k = 0; k < 4; ++k) a = fmaf(xa[k], W1[k * 32 + j], a);
            acc[j] = a;
        }
        unsigned m = 0;
#pragma unroll
        for (int j = 0; j < 32; ++j) {
            const bool p = acc[j] > 0.0f;
            m |= ((unsigned)(p ? 1 : 0)) << j;
            fbuf[j * 64 + lane] = p ? acc[j] : 0.0f;
        }
        m1 = m;
    }
    // ---- L2: 32 -> 32, in-place ----
    {
        float acc[32];
#pragma unroll
        for (int j = 0; j < 32; ++j) acc[j] = b2[j];
#pragma unroll 2
        for (int k = 0; k < 32; ++k) {
            const float cv = fbuf[k * 64 + lane];
#pragma unroll
            for (int j = 0; j < 32; ++j) acc[j] = fmaf(cv, W2[k * 32 + j], acc[j]);
        }
        unsigned m = 0;
#pragma unroll
        for (int j = 0; j < 32; ++j) {
            const bool p = acc[j] > 0.0f;
            m |= ((unsigned)(p ? 1 : 0)) << j;
            fbuf[j * 64 + lane] = p ? acc[j] : 0.0f;
        }
        m2 = m;
    }
    // ---- L3: 32 -> 64; units 0..33 to LDS, 34..63 stay in registers ----
    float h3r[64 - FWDU];
    {
        float acc[64];
#pragma unroll
        for (int j = 0; j < 64; ++j) acc[j] = b3[j];
#pragma unroll 2
        for (int k = 0; k < 32; ++k) {
            const float cv = fbuf[k * 64 + lane];
#pragma unroll
            for (int j = 0; j < 64; ++j) acc[j] = fmaf(cv, W3[k * 64 + j], acc[j]);
        }
        unsigned long long m = 0ULL;
#pragma unroll
        for (int j = 0; j < 64; ++j) {
            const bool p = acc[j] > 0.0f;
            m |= ((unsigned long long)(p ? 1 : 0)) << j;
            const float hv = p ? acc[j] : 0.0f;
            if (j < FWDU) fbuf[j * 64 + lane] = hv;
            else          h3r[j - FWDU] = hv;
        }
        m3 = m;
    }
    // ---- L4 + L5 fused: h4 never materialized ----
    {
        float acc[64];
#pragma unroll
        for (int j = 0; j < 64; ++j) acc[j] = b4[j];
#pragma unroll 2
        for (int k = 0; k < FWDU; ++k) {
            const float cv = fbuf[k * 64 + lane];
#pragma unroll
            for (int j = 0; j < 64; ++j) acc[j] = fmaf(cv, W4[k * 64 + j], acc[j]);
        }
#pragma unroll
        for (int t = 0; t < 64 - FWDU; ++t) {       // k = FWDU+t, compile-time
            const float cv = h3r[t];
#pragma unroll
            for (int j = 0; j < 64; ++j) acc[j] = fmaf(cv, W4[(FWDU + t) * 64 + j], acc[j]);
        }
        unsigned long long m = 0ULL;
        float y[4] = {b5[0], b5[1], b5[2], b5[3]};
#pragma unroll
        for (int j = 0; j < 64; ++j) {
            const bool p = acc[j] > 0.0f;
            m |= ((unsigned long long)(p ? 1 : 0)) << j;
            const float hv = p ? acc[j] : 0.0f;
#pragma unroll
            for (int i = 0; i < 4; ++i) y[i] = fmaf(hv, W5[j * 4 + i], y[i]);
        }
        m4 = m;
        float4 o;
        o.x = xa[0] + y[0]; o.y = xa[1] + y[1];
        o.z = xa[2] + y[2]; o.w = xa[3] + y[3];
        *reinterpret_cast<float4*>(out_state + 4 * s_my) = o;
    }
    // masks sample-major: epilogue reads 1-2 b32 per sample block
    mkS[lane * 6 + 0] = m1;
    mkS[lane * 6 + 1] = m2;
    mkS[lane * 6 + 2] = (unsigned)(m3 & 0xffffffffULL);
    mkS[lane * 6 + 3] = (unsigned)(m3 >> 32);
    mkS[lane * 6 + 4] = (unsigned)(m4 & 0xffffffffULL);
    mkS[lane * 6 + 5] = (unsigned)(m4 >> 32);

    // Keep tangent-phase weight fragments (64 VGPRs) out of the forward.
    __builtin_amdgcn_sched_barrier(0);

    // ============ phase 2: bf16 weight fragments in registers ==============
    // Identical data to rounds 2-7; now used as the A (W^T) operand.
    const int col = lane & 15, G = lane >> 4;
    short8 W2f[2], W3f[4], W4f[8], W5f[2];
#pragma unroll
    for (int mt = 0; mt < 2; ++mt) W2f[mt] = loadB(W2, 32, 32, 8 * G, 16 * mt + col);
#pragma unroll
    for (int mt = 0; mt < 4; ++mt) W3f[mt] = loadB(W3, 64, 32, 8 * G, 16 * mt + col);
#pragma unroll
    for (int kt = 0; kt < 2; ++kt)
#pragma unroll
        for (int mt = 0; mt < 4; ++mt)
            W4f[kt * 4 + mt] = loadB(W4, 64, 64, 32 * kt + 8 * G, 16 * mt + col);
#pragma unroll
    for (int kt = 0; kt < 2; ++kt) W5f[kt] = loadB(W5, 4, 64, 32 * kt + 8 * G, col);

    // ============ phase 3: one Jacobian column per pass ====================
    // T region = wb[0..8192) — overlaps the (now dead) fwd buffer.
    for (int r = 0; r < 4; ++r) {
        // T1[s][u] = m1[s][u] ? bf16(W1[r][u]) : 0 — direct masked seed write.
#pragma unroll
        for (int sl = 0; sl < 4; ++sl) {
            short8 v;
#pragma unroll
            for (int e = 0; e < 8; ++e) {
                const int u = sl * 8 + e;
                v[e] = ((m1 >> u) & 1u) ? (short)f2bf(W1[r * 32 + u]) : (short)0;
            }
            *(short8*)(wb + taddr(lane, sl)) = v;
        }
        // T2 = m2 .* (T1@W2); T3 = m3 .* (T2@W3); T4 = m4 .* (T3@W4)  [transposed]
        tan_layer_T<2, 1, 1, 1>(wb, mkS, W2f, lane);
        tan_layer_T<4, 1, 2, 2>(wb, mkS, W3f, lane);
        tan_layer_T<4, 2, 4, 2>(wb, mkS, W4f, lane);
        // F[:, :, r] = I[:, r] + T4 @ W5
        tan_final_T(wb, W5f, lane, r, out_F, sbase);
    }
}

extern "C" void kernel_launch(void* const* d_in, const int* in_sizes, int n_in,
                              void* d_out, int out_size, void* d_ws, size_t ws_size,
                              hipStream_t stream)
{
    const float* W1 = (const float*)d_in[0];
    const float* b1 = (const float*)d_in[1];
    const float* W2 = (const float*)d_in[2];
    const float* b2 = (const float*)d_in[3];
    const float* W3 = (const float*)d_in[4];
    const float* b3 = (const float*)d_in[5];
    const float* W4 = (const float*)d_in[6];
    const float* b4 = (const float*)d_in[7];
    const float* W5 = (const float*)d_in[8];
    const float* b5 = (const float*)d_in[9];
    const float* xin = (const float*)d_in[10];

    const int Btot = in_sizes[10] / 4;       // last_state is (B,1,4) fp32
    float* out_state = (float*)d_out;
    float* out_F = out_state + (size_t)Btot * 4;

    const int grid = (Btot + BLOCK - 1) / BLOCK;
    mlp_jac_kernel<<<grid, BLOCK, 0, stream>>>(
        W1, b1, W2, b2, W3, b3, W4, b4, W5, b5, xin, out_state, out_F, Btot);
}

// Round 9
// 104.617 us; speedup vs baseline: 5.0874x; 1.0359x over previous
//
#include <hip/hip_runtime.h>

typedef __attribute__((ext_vector_type(8))) short short8;
typedef __attribute__((ext_vector_type(4))) float f32x4;
typedef __attribute__((ext_vector_type(2))) unsigned uint2v;

#define NWAVES 2
#define BLOCK (64 * NWAVES)
#define TB 8192                     // tangent T buffer: 64 rows x 128 B bf16
#define FWDU 32                     // fwd units in LDS row (rest in regs)
#define FWDB 8192                   // fwd buf: 64 rows x 32 units x 4B — same 8KB as T
#define WBYTES (FWDB + 6 * 64 * 4)  // + masks mkS[64][6] -> 9728 B/wave

__device__ __forceinline__ unsigned short f2bf(float f) {
    unsigned u = __builtin_bit_cast(unsigned, f);
    u += 0x7FFFu + ((u >> 16) & 1u);          // round-to-nearest-even
    return (unsigned short)(u >> 16);
}

// swizzled row/slot byte address: row in [0,64), slot = 16B unit (8 slots/row).
// Used for BOTH the bf16 T buffer and the fp32 forward relay (identical layout).
__device__ __forceinline__ int taddr(int row, int slot) {
    return row * 128 + (((slot ^ (row & 7)) << 4));
}

// bf16 weight fragment: element [k][col] of W (row-major KxN), zero-padded.
__device__ __forceinline__ short8 loadB(const float* __restrict__ W, int Nout, int Kin,
                                        int kbase, int col) {
    short8 r;
#pragma unroll
    for (int i = 0; i < 8; ++i) {
        int k = kbase + i;
        float v = (k < Kin && col < Nout) ? W[k * Nout + col] : 0.0f;
        r[i] = (short)f2bf(v);
    }
    return r;
}

// ---------- transposed tangent layer: T_next^T = mask .* (W^T @ T^T) --------
template<int MT, int KT, int W0, int NW>
__device__ __forceinline__ void tan_layer_T(unsigned char* wb, const unsigned* mkS,
                                            const short8* Wf, int lane)
{
    const int G = lane >> 4, sl = lane & 15;
#pragma unroll
    for (int nt = 0; nt < 4; ++nt) {
        const int s = nt * 16 + sl;                    // sample row
        short8 bt[KT];
#pragma unroll
        for (int kt = 0; kt < KT; ++kt)
            bt[kt] = *(const short8*)(wb + taddr(s, 4 * kt + G));
        unsigned mwords[NW];
#pragma unroll
        for (int w = 0; w < NW; ++w) mwords[w] = mkS[s * 6 + W0 + w];
#pragma unroll
        for (int mt = 0; mt < MT; ++mt) {
            f32x4 c = {0.f, 0.f, 0.f, 0.f};
#pragma unroll
            for (int kt = 0; kt < KT; ++kt)
                c = __builtin_amdgcn_mfma_f32_16x16x32_bf16(Wf[kt * MT + mt], bt[kt], c, 0, 0, 0);
            // mask + pack + single b64 write of units u0..u0+3 of sample s
            const unsigned mw = mwords[(mt * 16) >> 5] >> ((mt & 1) * 16 + G * 4);
            const float v0 = (mw & 1u) ? c[0] : 0.0f;
            const float v1 = (mw & 2u) ? c[1] : 0.0f;
            const float v2 = (mw & 4u) ? c[2] : 0.0f;
            const float v3 = (mw & 8u) ? c[3] : 0.0f;
            unsigned lo, hi;
            asm("v_cvt_pk_bf16_f32 %0, %1, %2" : "=v"(lo) : "v"(v0), "v"(v1));
            asm("v_cvt_pk_bf16_f32 %0, %1, %2" : "=v"(hi) : "v"(v2), "v"(v3));
            const int slot = 2 * mt + (G >> 1);
            uint2v pk; pk[0] = lo; pk[1] = hi;
            *(uint2v*)(wb + s * 128 + ((slot ^ (s & 7)) << 4) + 8 * (G & 1)) = pk;
        }
    }
}

// ---------- final layer (transposed): F col r = I[:,r] + (W5^T @ T4^T)^T ----
__device__ __forceinline__ void tan_final_T(unsigned char* wb, const short8* B5,
                                            int lane, int r,
                                            float* __restrict__ out_F, int sbase)
{
    const int G = lane >> 4, sl = lane & 15;
#pragma unroll
    for (int nt = 0; nt < 4; ++nt) {
        const int s = nt * 16 + sl;
        short8 b0 = *(const short8*)(wb + taddr(s, G));
        short8 b1 = *(const short8*)(wb + taddr(s, 4 + G));
        f32x4 c = {0.f, 0.f, 0.f, 0.f};
        c = __builtin_amdgcn_mfma_f32_16x16x32_bf16(B5[0], b0, c, 0, 0, 0);
        c = __builtin_amdgcn_mfma_f32_16x16x32_bf16(B5[1], b1, c, 0, 0, 0);
        if (G == 0) {                                  // rows 0-3 = out dims
#pragma unroll
            for (int i = 0; i < 4; ++i)
                out_F[(size_t)(sbase + s) * 16 + i * 4 + r] = c[i] + ((i == r) ? 1.0f : 0.0f);
        }
    }
}

__global__ __launch_bounds__(BLOCK)
void mlp_jac_kernel(
    const float* __restrict__ W1, const float* __restrict__ b1,
    const float* __restrict__ W2, const float* __restrict__ b2,
    const float* __restrict__ W3, const float* __restrict__ b3,
    const float* __restrict__ W4, const float* __restrict__ b4,
    const float* __restrict__ W5, const float* __restrict__ b5,
    const float* __restrict__ xin,
    float* __restrict__ out_state, float* __restrict__ out_F, int Btot)
{
    __shared__ __align__(16) unsigned char smem[NWAVES][WBYTES];
    const int tid = threadIdx.x;
    const int wid = tid >> 6;
    const int lane = tid & 63;
    const int sbase = blockIdx.x * BLOCK + wid * 64;   // wave's first sample
    if (sbase >= Btot) return;

    unsigned char* wb = smem[wid];
    unsigned* mkS = (unsigned*)(wb + FWDB);            // masks, sample-major [s][6]

    const int s_my = sbase + lane;
    const float4 xv = *reinterpret_cast<const float4*>(xin + 4 * s_my);
    const float xa[4] = {xv.x, xv.y, xv.z, xv.w};

    // ============ phase 1: fp32 forward, row-major b128 LDS relay ==========
    // Each lane's activations live in ITS OWN swizzled 128B row: one
    // ds_read_b128 feeds 4 k-iterations (vs 1 per ds_read_b32 in r7/r8).
    // Accumulation order (k ascending) unchanged -> bit-identical results.
    unsigned m1, m2;
    unsigned long long m3, m4;
    // ---- L1: 4 -> 32 ----
    {
        float acc[32];
#pragma unroll
        for (int j = 0; j < 32; ++j) {
            float a = b1[j];
#pragma unroll
            for (int k = 0; k < 4; ++k) a = fmaf(xa[k], W1[k * 32 + j], a);
            acc[j] = a;
        }
        unsigned m = 0;
#pragma unroll
        for (int j = 0; j < 32; ++j) {
            const bool p = acc[j] > 0.0f;
            m |= ((unsigned)(p ? 1 : 0)) << j;
            acc[j] = p ? acc[j] : 0.0f;
        }
#pragma unroll
        for (int jb = 0; jb < 8; ++jb) {
            float4 v; v.x = acc[4*jb]; v.y = acc[4*jb+1]; v.z = acc[4*jb+2]; v.w = acc[4*jb+3];
            *(float4*)(wb + taddr(lane, jb)) = v;
        }
        m1 = m;
    }
    // ---- L2: 32 -> 32, in-place (reads complete before writes, same lane) --
    {
        float acc[32];
#pragma unroll
        for (int j = 0; j < 32; ++j) acc[j] = b2[j];
#pragma unroll 2
        for (int kb = 0; kb < 8; ++kb) {
            const float4 cv4 = *(const float4*)(wb + taddr(lane, kb));
            const float cvs[4] = {cv4.x, cv4.y, cv4.z, cv4.w};
#pragma unroll
            for (int ki = 0; ki < 4; ++ki) {
                const float cv = cvs[ki];
                const int k = 4 * kb + ki;
#pragma unroll
                for (int j = 0; j < 32; ++j) acc[j] = fmaf(cv, W2[k * 32 + j], acc[j]);
            }
        }
        unsigned m = 0;
#pragma unroll
        for (int j = 0; j < 32; ++j) {
            const bool p = acc[j] > 0.0f;
            m |= ((unsigned)(p ? 1 : 0)) << j;
            acc[j] = p ? acc[j] : 0.0f;
        }
#pragma unroll
        for (int jb = 0; jb < 8; ++jb) {
            float4 v; v.x = acc[4*jb]; v.y = acc[4*jb+1]; v.z = acc[4*jb+2]; v.w = acc[4*jb+3];
            *(float4*)(wb + taddr(lane, jb)) = v;
        }
        m2 = m;
    }
    // ---- L3: 32 -> 64; units 0..31 to LDS row, 32..63 stay in registers ----
    float h3r[32];
    {
        float acc[64];
#pragma unroll
        for (int j = 0; j < 64; ++j) acc[j] = b3[j];
#pragma unroll 2
        for (int kb = 0; kb < 8; ++kb) {
            const float4 cv4 = *(const float4*)(wb + taddr(lane, kb));
            const float cvs[4] = {cv4.x, cv4.y, cv4.z, cv4.w};
#pragma unroll
            for (int ki = 0; ki < 4; ++ki) {
                const float cv = cvs[ki];
                const int k = 4 * kb + ki;
#pragma unroll
                for (int j = 0; j < 64; ++j) acc[j] = fmaf(cv, W3[k * 64 + j], acc[j]);
            }
        }
        unsigned long long m = 0ULL;
#pragma unroll
        for (int j = 0; j < 64; ++j) {
            const bool p = acc[j] > 0.0f;
            m |= ((unsigned long long)(p ? 1 : 0)) << j;
            acc[j] = p ? acc[j] : 0.0f;
        }
#pragma unroll
        for (int jb = 0; jb < 8; ++jb) {
            float4 v; v.x = acc[4*jb]; v.y = acc[4*jb+1]; v.z = acc[4*jb+2]; v.w = acc[4*jb+3];
            *(float4*)(wb + taddr(lane, jb)) = v;
        }
#pragma unroll
        for (int t = 0; t < 32; ++t) h3r[t] = acc[32 + t];
        m3 = m;
    }
    // ---- L4 + L5 fused: h4 never materialized ----
    {
        float acc[64];
#pragma unroll
        for (int j = 0; j < 64; ++j) acc[j] = b4[j];
#pragma unroll 2
        for (int kb = 0; kb < 8; ++kb) {
            const float4 cv4 = *(const float4*)(wb + taddr(lane, kb));
            const float cvs[4] = {cv4.x, cv4.y, cv4.z, cv4.w};
#pragma unroll
            for (int ki = 0; ki < 4; ++ki) {
                const float cv = cvs[ki];
                const int k = 4 * kb + ki;
#pragma unroll
                for (int j = 0; j < 64; ++j) acc[j] = fmaf(cv, W4[k * 64 + j], acc[j]);
            }
        }
#pragma unroll
        for (int t = 0; t < 32; ++t) {              // k = 32+t, compile-time
            const float cv = h3r[t];
#pragma unroll
            for (int j = 0; j < 64; ++j) acc[j] = fmaf(cv, W4[(32 + t) * 64 + j], acc[j]);
        }
        unsigned long long m = 0ULL;
        float y[4] = {b5[0], b5[1], b5[2], b5[3]};
#pragma unroll
        for (int j = 0; j < 64; ++j) {
            const bool p = acc[j] > 0.0f;
            m |= ((unsigned long long)(p ? 1 : 0)) << j;
            const float hv = p ? acc[j] : 0.0f;
#pragma unroll
            for (int i = 0; i < 4; ++i) y[i] = fmaf(hv, W5[j * 4 + i], y[i]);
        }
        m4 = m;
        float4 o;
        o.x = xa[0] + y[0]; o.y = xa[1] + y[1];
        o.z = xa[2] + y[2]; o.w = xa[3] + y[3];
        *reinterpret_cast<float4*>(out_state + 4 * s_my) = o;
    }
    // masks sample-major: epilogue reads 1-2 b32 per sample block
    mkS[lane * 6 + 0] = m1;
    mkS[lane * 6 + 1] = m2;
    mkS[lane * 6 + 2] = (unsigned)(m3 & 0xffffffffULL);
    mkS[lane * 6 + 3] = (unsigned)(m3 >> 32);
    mkS[lane * 6 + 4] = (unsigned)(m4 & 0xffffffffULL);
    mkS[lane * 6 + 5] = (unsigned)(m4 >> 32);

    // Keep tangent-phase weight fragments (64 VGPRs) out of the forward.
    __builtin_amdgcn_sched_barrier(0);

    // ============ phase 2: bf16 weight fragments in registers ==============
    const int col = lane & 15, G = lane >> 4;
    short8 W2f[2], W3f[4], W4f[8], W5f[2];
#pragma unroll
    for (int mt = 0; mt < 2; ++mt) W2f[mt] = loadB(W2, 32, 32, 8 * G, 16 * mt + col);
#pragma unroll
    for (int mt = 0; mt < 4; ++mt) W3f[mt] = loadB(W3, 64, 32, 8 * G, 16 * mt + col);
#pragma unroll
    for (int kt = 0; kt < 2; ++kt)
#pragma unroll
        for (int mt = 0; mt < 4; ++mt)
            W4f[kt * 4 + mt] = loadB(W4, 64, 64, 32 * kt + 8 * G, 16 * mt + col);
#pragma unroll
    for (int kt = 0; kt < 2; ++kt) W5f[kt] = loadB(W5, 4, 64, 32 * kt + 8 * G, col);

    // ============ phase 3: one Jacobian column per pass ====================
    // T region = wb[0..8192) — overlaps the (now dead) fwd buffer.
    for (int r = 0; r < 4; ++r) {
        // T1[s][u] = m1[s][u] ? bf16(W1[r][u]) : 0 — direct masked seed write.
#pragma unroll
        for (int sl = 0; sl < 4; ++sl) {
            short8 v;
#pragma unroll
            for (int e = 0; e < 8; ++e) {
                const int u = sl * 8 + e;
                v[e] = ((m1 >> u) & 1u) ? (short)f2bf(W1[r * 32 + u]) : (short)0;
            }
            *(short8*)(wb + taddr(lane, sl)) = v;
        }
        // T2 = m2 .* (T1@W2); T3 = m3 .* (T2@W3); T4 = m4 .* (T3@W4)  [transposed]
        tan_layer_T<2, 1, 1, 1>(wb, mkS, W2f, lane);
        tan_layer_T<4, 1, 2, 2>(wb, mkS, W3f, lane);
        tan_layer_T<4, 2, 4, 2>(wb, mkS, W4f, lane);
        // F[:, :, r] = I[:, r] + T4 @ W5
        tan_final_T(wb, W5f, lane, r, out_F, sbase);
    }
}

extern "C" void kernel_launch(void* const* d_in, const int* in_sizes, int n_in,
                              void* d_out, int out_size, void* d_ws, size_t ws_size,
                              hipStream_t stream)
{
    const float* W1 = (const float*)d_in[0];
    const float* b1 = (const float*)d_in[1];
    const float* W2 = (const float*)d_in[2];
    const float* b2 = (const float*)d_in[3];
    const float* W3 = (const float*)d_in[4];
    const float* b3 = (const float*)d_in[5];
    const float* W4 = (const float*)d_in[6];
    const float* b4 = (const float*)d_in[7];
    const float* W5 = (const float*)d_in[8];
    const float* b5 = (const float*)d_in[9];
    const float* xin = (const float*)d_in[10];

    const int Btot = in_sizes[10] / 4;       // last_state is (B,1,4) fp32
    float* out_state = (float*)d_out;
    float* out_F = out_state + (size_t)Btot * 4;

    const int grid = (Btot + BLOCK - 1) / BLOCK;
    mlp_jac_kernel<<<grid, BLOCK, 0, stream>>>(
        W1, b1, W2, b2, W3, b3, W4, b4, W5, b5, xin, out_state, out_F, Btot);
}

// Round 10
// 102.050 us; speedup vs baseline: 5.2154x; 1.0252x over previous
//
#include <hip/hip_runtime.h>

typedef __attribute__((ext_vector_type(8))) short short8;
typedef __attribute__((ext_vector_type(4))) float f32x4;
typedef __attribute__((ext_vector_type(2))) float f32x2;
typedef __attribute__((ext_vector_type(2))) unsigned uint2v;

#define NWAVES 2
#define BLOCK (64 * NWAVES)
#define TB 8192                     // tangent T buffer: 64 rows x 128 B bf16
#define FWDB 8192                   // fwd buf: 64 rows x 32 units x 4B — same 8KB as T
#define WBYTES (FWDB + 6 * 64 * 4)  // + masks mkS[64][6] -> 9728 B/wave

__device__ __forceinline__ unsigned short f2bf(float f) {
    unsigned u = __builtin_bit_cast(unsigned, f);
    u += 0x7FFFu + ((u >> 16) & 1u);          // round-to-nearest-even
    return (unsigned short)(u >> 16);
}

// swizzled row/slot byte address: row in [0,64), slot = 16B unit (8 slots/row).
__device__ __forceinline__ int taddr(int row, int slot) {
    return row * 128 + (((slot ^ (row & 7)) << 4));
}

// packed fp32 fma: compiles to v_pk_fma_f32 on gfx90a+ (2 FLOP/lane/cycle).
__device__ __forceinline__ f32x2 pkfma(f32x2 a, f32x2 b, f32x2 c) {
    return __builtin_elementwise_fma(a, b, c);
}

// bf16 weight fragment: element [k][col] of W (row-major KxN), zero-padded.
__device__ __forceinline__ short8 loadB(const float* __restrict__ W, int Nout, int Kin,
                                        int kbase, int col) {
    short8 r;
#pragma unroll
    for (int i = 0; i < 8; ++i) {
        int k = kbase + i;
        float v = (k < Kin && col < Nout) ? W[k * Nout + col] : 0.0f;
        r[i] = (short)f2bf(v);
    }
    return r;
}

// ---------- transposed tangent layer: T_next^T = mask .* (W^T @ T^T) --------
template<int MT, int KT, int W0, int NW>
__device__ __forceinline__ void tan_layer_T(unsigned char* wb, const unsigned* mkS,
                                            const short8* Wf, int lane)
{
    const int G = lane >> 4, sl = lane & 15;
#pragma unroll
    for (int nt = 0; nt < 4; ++nt) {
        const int s = nt * 16 + sl;                    // sample row
        short8 bt[KT];
#pragma unroll
        for (int kt = 0; kt < KT; ++kt)
            bt[kt] = *(const short8*)(wb + taddr(s, 4 * kt + G));
        unsigned mwords[NW];
#pragma unroll
        for (int w = 0; w < NW; ++w) mwords[w] = mkS[s * 6 + W0 + w];
#pragma unroll
        for (int mt = 0; mt < MT; ++mt) {
            f32x4 c = {0.f, 0.f, 0.f, 0.f};
#pragma unroll
            for (int kt = 0; kt < KT; ++kt)
                c = __builtin_amdgcn_mfma_f32_16x16x32_bf16(Wf[kt * MT + mt], bt[kt], c, 0, 0, 0);
            // mask + pack + single b64 write of units u0..u0+3 of sample s
            const unsigned mw = mwords[(mt * 16) >> 5] >> ((mt & 1) * 16 + G * 4);
            const float v0 = (mw & 1u) ? c[0] : 0.0f;
            const float v1 = (mw & 2u) ? c[1] : 0.0f;
            const float v2 = (mw & 4u) ? c[2] : 0.0f;
            const float v3 = (mw & 8u) ? c[3] : 0.0f;
            unsigned lo, hi;
            asm("v_cvt_pk_bf16_f32 %0, %1, %2" : "=v"(lo) : "v"(v0), "v"(v1));
            asm("v_cvt_pk_bf16_f32 %0, %1, %2" : "=v"(hi) : "v"(v2), "v"(v3));
            const int slot = 2 * mt + (G >> 1);
            uint2v pk; pk[0] = lo; pk[1] = hi;
            *(uint2v*)(wb + s * 128 + ((slot ^ (s & 7)) << 4) + 8 * (G & 1)) = pk;
        }
    }
}

// ---------- final layer (transposed): F col r = I[:,r] + (W5^T @ T4^T)^T ----
__device__ __forceinline__ void tan_final_T(unsigned char* wb, const short8* B5,
                                            int lane, int r,
                                            float* __restrict__ out_F, int sbase)
{
    const int G = lane >> 4, sl = lane & 15;
#pragma unroll
    for (int nt = 0; nt < 4; ++nt) {
        const int s = nt * 16 + sl;
        short8 b0 = *(const short8*)(wb + taddr(s, G));
        short8 b1 = *(const short8*)(wb + taddr(s, 4 + G));
        f32x4 c = {0.f, 0.f, 0.f, 0.f};
        c = __builtin_amdgcn_mfma_f32_16x16x32_bf16(B5[0], b0, c, 0, 0, 0);
        c = __builtin_amdgcn_mfma_f32_16x16x32_bf16(B5[1], b1, c, 0, 0, 0);
        if (G == 0) {                                  // rows 0-3 = out dims
#pragma unroll
            for (int i = 0; i < 4; ++i)
                out_F[(size_t)(sbase + s) * 16 + i * 4 + r] = c[i] + ((i == r) ? 1.0f : 0.0f);
        }
    }
}

__global__ __launch_bounds__(BLOCK)
void mlp_jac_kernel(
    const float* __restrict__ W1, const float* __restrict__ b1,
    const float* __restrict__ W2, const float* __restrict__ b2,
    const float* __restrict__ W3, const float* __restrict__ b3,
    const float* __restrict__ W4, const float* __restrict__ b4,
    const float* __restrict__ W5, const float* __restrict__ b5,
    const float* __restrict__ xin,
    float* __restrict__ out_state, float* __restrict__ out_F, int Btot)
{
    __shared__ __align__(16) unsigned char smem[NWAVES][WBYTES];
    const int tid = threadIdx.x;
    const int wid = tid >> 6;
    const int lane = tid & 63;
    const int sbase = blockIdx.x * BLOCK + wid * 64;   // wave's first sample
    if (sbase >= Btot) return;

    unsigned char* wb = smem[wid];
    unsigned* mkS = (unsigned*)(wb + FWDB);            // masks, sample-major [s][6]

    const int s_my = sbase + lane;
    const float4 xv = *reinterpret_cast<const float4*>(xin + 4 * s_my);
    const float xa[4] = {xv.x, xv.y, xv.z, xv.w};

    // ============ phase 1: fp32 forward, b128 LDS relay + packed fma =======
    // Inner j-loops run on f32x2 pairs -> v_pk_fma_f32 (2 FLOP/lane/cy).
    // Same per-element fma, same k-then-j order -> bit-identical to r9.
    unsigned m1, m2;
    unsigned long long m3, m4;
    // ---- L1: 4 -> 32 (small, scalar) ----
    {
        float acc[32];
#pragma unroll
        for (int j = 0; j < 32; ++j) {
            float a = b1[j];
#pragma unroll
            for (int k = 0; k < 4; ++k) a = fmaf(xa[k], W1[k * 32 + j], a);
            acc[j] = a;
        }
        unsigned m = 0;
#pragma unroll
        for (int j = 0; j < 32; ++j) {
            const bool p = acc[j] > 0.0f;
            m |= ((unsigned)(p ? 1 : 0)) << j;
            acc[j] = p ? acc[j] : 0.0f;
        }
#pragma unroll
        for (int jb = 0; jb < 8; ++jb) {
            float4 v; v.x = acc[4*jb]; v.y = acc[4*jb+1]; v.z = acc[4*jb+2]; v.w = acc[4*jb+3];
            *(float4*)(wb + taddr(lane, jb)) = v;
        }
        m1 = m;
    }
    // ---- L2: 32 -> 32, packed ----
    {
        f32x2 acc[16];
#pragma unroll
        for (int j = 0; j < 16; ++j) { acc[j][0] = b2[2*j]; acc[j][1] = b2[2*j+1]; }
#pragma unroll 2
        for (int kb = 0; kb < 8; ++kb) {
            const float4 cv4 = *(const float4*)(wb + taddr(lane, kb));
            const float cvs[4] = {cv4.x, cv4.y, cv4.z, cv4.w};
#pragma unroll
            for (int ki = 0; ki < 4; ++ki) {
                const f32x2 cv = {cvs[ki], cvs[ki]};
                const int k = 4 * kb + ki;
#pragma unroll
                for (int j = 0; j < 16; ++j)
                    acc[j] = pkfma(cv, *(const f32x2*)(W2 + k * 32 + 2 * j), acc[j]);
            }
        }
        unsigned m = 0;
#pragma unroll
        for (int j = 0; j < 16; ++j) {
            const bool p0 = acc[j][0] > 0.0f, p1 = acc[j][1] > 0.0f;
            m |= ((unsigned)(p0 ? 1 : 0)) << (2*j);
            m |= ((unsigned)(p1 ? 1 : 0)) << (2*j+1);
            acc[j][0] = p0 ? acc[j][0] : 0.0f;
            acc[j][1] = p1 ? acc[j][1] : 0.0f;
        }
#pragma unroll
        for (int jb = 0; jb < 8; ++jb) {
            float4 v; v.x = acc[2*jb][0]; v.y = acc[2*jb][1]; v.z = acc[2*jb+1][0]; v.w = acc[2*jb+1][1];
            *(float4*)(wb + taddr(lane, jb)) = v;
        }
        m2 = m;
    }
    // ---- L3: 32 -> 64, packed; units 0..31 to LDS, 32..63 stay in regs ----
    f32x2 h3r[16];
    {
        f32x2 acc[32];
#pragma unroll
        for (int j = 0; j < 32; ++j) { acc[j][0] = b3[2*j]; acc[j][1] = b3[2*j+1]; }
#pragma unroll 2
        for (int kb = 0; kb < 8; ++kb) {
            const float4 cv4 = *(const float4*)(wb + taddr(lane, kb));
            const float cvs[4] = {cv4.x, cv4.y, cv4.z, cv4.w};
#pragma unroll
            for (int ki = 0; ki < 4; ++ki) {
                const f32x2 cv = {cvs[ki], cvs[ki]};
                const int k = 4 * kb + ki;
#pragma unroll
                for (int j = 0; j < 32; ++j)
                    acc[j] = pkfma(cv, *(const f32x2*)(W3 + k * 64 + 2 * j), acc[j]);
            }
        }
        unsigned long long m = 0ULL;
#pragma unroll
        for (int j = 0; j < 32; ++j) {
            const bool p0 = acc[j][0] > 0.0f, p1 = acc[j][1] > 0.0f;
            m |= ((unsigned long long)(p0 ? 1 : 0)) << (2*j);
            m |= ((unsigned long long)(p1 ? 1 : 0)) << (2*j+1);
            acc[j][0] = p0 ? acc[j][0] : 0.0f;
            acc[j][1] = p1 ? acc[j][1] : 0.0f;
        }
#pragma unroll
        for (int jb = 0; jb < 8; ++jb) {
            float4 v; v.x = acc[2*jb][0]; v.y = acc[2*jb][1]; v.z = acc[2*jb+1][0]; v.w = acc[2*jb+1][1];
            *(float4*)(wb + taddr(lane, jb)) = v;
        }
#pragma unroll
        for (int t = 0; t < 16; ++t) h3r[t] = acc[16 + t];
        m3 = m;
    }
    // ---- L4 + L5 fused, packed: h4 never materialized ----
    {
        f32x2 acc[32];
#pragma unroll
        for (int j = 0; j < 32; ++j) { acc[j][0] = b4[2*j]; acc[j][1] = b4[2*j+1]; }
#pragma unroll 2
        for (int kb = 0; kb < 8; ++kb) {
            const float4 cv4 = *(const float4*)(wb + taddr(lane, kb));
            const float cvs[4] = {cv4.x, cv4.y, cv4.z, cv4.w};
#pragma unroll
            for (int ki = 0; ki < 4; ++ki) {
                const f32x2 cv = {cvs[ki], cvs[ki]};
                const int k = 4 * kb + ki;
#pragma unroll
                for (int j = 0; j < 32; ++j)
                    acc[j] = pkfma(cv, *(const f32x2*)(W4 + k * 64 + 2 * j), acc[j]);
            }
        }
#pragma unroll
        for (int t = 0; t < 32; ++t) {              // k = 32+t, compile-time
            const float cs = h3r[t >> 1][t & 1];
            const f32x2 cv = {cs, cs};
#pragma unroll
            for (int j = 0; j < 32; ++j)
                acc[j] = pkfma(cv, *(const f32x2*)(W4 + (32 + t) * 64 + 2 * j), acc[j]);
        }
        unsigned long long m = 0ULL;
        f32x2 y01 = {b5[0], b5[1]}, y23 = {b5[2], b5[3]};
#pragma unroll
        for (int j = 0; j < 32; ++j) {
#pragma unroll
            for (int e = 0; e < 2; ++e) {
                const int u = 2 * j + e;
                const bool p = acc[j][e] > 0.0f;
                m |= ((unsigned long long)(p ? 1 : 0)) << u;
                const float hv = p ? acc[j][e] : 0.0f;
                const f32x2 hvv = {hv, hv};
                y01 = pkfma(hvv, *(const f32x2*)(W5 + u * 4), y01);
                y23 = pkfma(hvv, *(const f32x2*)(W5 + u * 4 + 2), y23);
            }
        }
        m4 = m;
        float4 o;
        o.x = xa[0] + y01[0]; o.y = xa[1] + y01[1];
        o.z = xa[2] + y23[0]; o.w = xa[3] + y23[1];
        *reinterpret_cast<float4*>(out_state + 4 * s_my) = o;
    }
    // masks sample-major: epilogue reads 1-2 b32 per sample block
    mkS[lane * 6 + 0] = m1;
    mkS[lane * 6 + 1] = m2;
    mkS[lane * 6 + 2] = (unsigned)(m3 & 0xffffffffULL);
    mkS[lane * 6 + 3] = (unsigned)(m3 >> 32);
    mkS[lane * 6 + 4] = (unsigned)(m4 & 0xffffffffULL);
    mkS[lane * 6 + 5] = (unsigned)(m4 >> 32);

    // Keep tangent-phase weight fragments (64 VGPRs) out of the forward.
    __builtin_amdgcn_sched_barrier(0);

    // ============ phase 2: bf16 weight fragments in registers ==============
    const int col = lane & 15, G = lane >> 4;
    short8 W2f[2], W3f[4], W4f[8], W5f[2];
#pragma unroll
    for (int mt = 0; mt < 2; ++mt) W2f[mt] = loadB(W2, 32, 32, 8 * G, 16 * mt + col);
#pragma unroll
    for (int mt = 0; mt < 4; ++mt) W3f[mt] = loadB(W3, 64, 32, 8 * G, 16 * mt + col);
#pragma unroll
    for (int kt = 0; kt < 2; ++kt)
#pragma unroll
        for (int mt = 0; mt < 4; ++mt)
            W4f[kt * 4 + mt] = loadB(W4, 64, 64, 32 * kt + 8 * G, 16 * mt + col);
#pragma unroll
    for (int kt = 0; kt < 2; ++kt) W5f[kt] = loadB(W5, 4, 64, 32 * kt + 8 * G, col);

    // ============ phase 3: one Jacobian column per pass ====================
    // T region = wb[0..8192) — overlaps the (now dead) fwd buffer.
    for (int r = 0; r < 4; ++r) {
        // T1[s][u] = m1[s][u] ? bf16(W1[r][u]) : 0 — direct masked seed write.
#pragma unroll
        for (int sl = 0; sl < 4; ++sl) {
            short8 v;
#pragma unroll
            for (int e = 0; e < 8; ++e) {
                const int u = sl * 8 + e;
                v[e] = ((m1 >> u) & 1u) ? (short)f2bf(W1[r * 32 + u]) : (short)0;
            }
            *(short8*)(wb + taddr(lane, sl)) = v;
        }
        // T2 = m2 .* (T1@W2); T3 = m3 .* (T2@W3); T4 = m4 .* (T3@W4)  [transposed]
        tan_layer_T<2, 1, 1, 1>(wb, mkS, W2f, lane);
        tan_layer_T<4, 1, 2, 2>(wb, mkS, W3f, lane);
        tan_layer_T<4, 2, 4, 2>(wb, mkS, W4f, lane);
        // F[:, :, r] = I[:, r] + T4 @ W5
        tan_final_T(wb, W5f, lane, r, out_F, sbase);
    }
}

extern "C" void kernel_launch(void* const* d_in, const int* in_sizes, int n_in,
                              void* d_out, int out_size, void* d_ws, size_t ws_size,
                              hipStream_t stream)
{
    const float* W1 = (const float*)d_in[0];
    const float* b1 = (const float*)d_in[1];
    const float* W2 = (const float*)d_in[2];
    const float* b2 = (const float*)d_in[3];
    const float* W3 = (const float*)d_in[4];
    const float* b3 = (const float*)d_in[5];
    const float* W4 = (const float*)d_in[6];
    const float* b4 = (const float*)d_in[7];
    const float* W5 = (const float*)d_in[8];
    const float* b5 = (const float*)d_in[9];
    const float* xin = (const float*)d_in[10];

    const int Btot = in_sizes[10] / 4;       // last_state is (B,1,4) fp32
    float* out_state = (float*)d_out;
    float* out_F = out_state + (size_t)Btot * 4;

    const int grid = (Btot + BLOCK - 1) / BLOCK;
    mlp_jac_kernel<<<grid, BLOCK, 0, stream>>>(
        W1, b1, W2, b2, W3, b3, W4, b4, W5, b5, xin, out_state, out_F, Btot);
}